// Round 4
// baseline (369.188 us; speedup 1.0000x reference)
//
#include <hip/hip_runtime.h>
#include <hip/hip_fp16.h>
#include <math.h>

#define H 4
#define C 64
#define HC 256
#define NEG 0.2f

// ---------------------------------------------------------------------------
// init: dst histogram (counts pre-zeroed; self-loop +1 folded into scan),
// partial sum of edge_attr, Kh[h]=dot(lin_edge_w[h],att_edge[h]),
// PQ[k][o] = sum_c W[k][ (o&3)*64+c ] * att_{src|dst}[(o&3)][c]  (o<4: src)
__global__ void init_kernel(const int* __restrict__ ei,
                            const float* __restrict__ edge_attr,
                            const float* __restrict__ lin_edge_w,
                            const float* __restrict__ att_edge,
                            const float* __restrict__ W,
                            const float* __restrict__ att_src,
                            const float* __restrict__ att_dst,
                            int* __restrict__ counts, float* __restrict__ mean_acc,
                            float* __restrict__ Kh, float* __restrict__ PQ, int Ee) {
    int gid = blockIdx.x * blockDim.x + threadIdx.x;
    int stride = gridDim.x * blockDim.x;
    float s = 0.f;
    for (int i = gid; i < Ee; i += stride) {
        s += edge_attr[i];
        atomicAdd(&counts[ei[Ee + i]], 1);
    }
    __shared__ float red[256];
    red[threadIdx.x] = s;
    __syncthreads();
    for (int off = 128; off; off >>= 1) {
        if (threadIdx.x < off) red[threadIdx.x] += red[threadIdx.x + off];
        __syncthreads();
    }
    if (threadIdx.x == 0) atomicAdd(mean_acc, red[0]);
    if (gid < H) {
        float k = 0.f;
        for (int c = 0; c < C; ++c) k += lin_edge_w[gid * C + c] * att_edge[gid * C + c];
        Kh[gid] = k;
    }
    if (gid < 512) {
        int k = gid >> 3, o = gid & 7;
        const float* att = (o < 4) ? att_src + o * C : att_dst + (o - 4) * C;
        const float* wr = W + k * HC + (o & 3) * C;
        float a = 0.f;
        for (int c = 0; c < C; ++c) a += wr[c] * att[c];
        PQ[gid] = a;
    }
}

// ---------------------------------------------------------------------------
// hierarchical scan of (counts[i] + 1) over Nn elements, 256/block
__global__ __launch_bounds__(256) void scan1_kernel(const int* __restrict__ counts,
                                                    int* __restrict__ blockSums, int Nn) {
    int idx = blockIdx.x * 256 + threadIdx.x;
    int v = (idx < Nn) ? counts[idx] + 1 : 0;
#pragma unroll
    for (int off = 32; off; off >>= 1) v += __shfl_down(v, off);
    __shared__ int ws[4];
    if ((threadIdx.x & 63) == 0) ws[threadIdx.x >> 6] = v;
    __syncthreads();
    if (threadIdx.x == 0) blockSums[blockIdx.x] = ws[0] + ws[1] + ws[2] + ws[3];
}

__global__ __launch_bounds__(256) void scan2_kernel(int* __restrict__ blockSums,
                                                    int* __restrict__ blockOff,
                                                    int* __restrict__ off,
                                                    int numBlocks, int Nn) {
    __shared__ int buf[2][256];
    int t = threadIdx.x;
    int v = (t < numBlocks) ? blockSums[t] : 0;
    buf[0][t] = v;
    __syncthreads();
    int pp = 0;
#pragma unroll
    for (int d = 1; d < 256; d <<= 1) {
        int nv = buf[pp][t];
        if (t >= d) nv += buf[pp][t - d];
        buf[pp ^ 1][t] = nv;
        pp ^= 1;
        __syncthreads();
    }
    int incl = buf[pp][t];
    if (t < numBlocks) blockOff[t] = incl - v;
    if (t == 255) off[Nn] = incl;  // grand total
}

__global__ __launch_bounds__(256) void scan3_kernel(const int* __restrict__ counts,
                                                    const int* __restrict__ blockOff,
                                                    int* __restrict__ off,
                                                    int* __restrict__ cursor, int Nn) {
    __shared__ int buf[2][256];
    int t = threadIdx.x;
    int idx = blockIdx.x * 256 + t;
    int v = (idx < Nn) ? counts[idx] + 1 : 0;
    buf[0][t] = v;
    __syncthreads();
    int pp = 0;
#pragma unroll
    for (int d = 1; d < 256; d <<= 1) {
        int nv = buf[pp][t];
        if (t >= d) nv += buf[pp][t - d];
        buf[pp ^ 1][t] = nv;
        pp ^= 1;
        __syncthreads();
    }
    if (idx < Nn) {
        int excl = blockOff[blockIdx.x] + buf[pp][t] - v;
        off[idx] = excl;
        cursor[idx] = excl;
    }
}

// ---------------------------------------------------------------------------
// h = x @ W (fp16 out). One node per block-iteration; x row address is
// block-uniform -> compiler scalarizes to s_load (SGPR row), each thread does a
// 64-FMA dot vs its register-resident W column. No LDS, no barriers, no shfl.
// Threads 0..7 additionally project the row through PQ -> a_src/a_dst.
__global__ __launch_bounds__(256) void gemm_kernel(
    const float* __restrict__ x, const float* __restrict__ W,
    const float* __restrict__ PQ, __half* __restrict__ h,
    float* __restrict__ a_src, float* __restrict__ a_dst, int Nn) {
    int t = threadIdx.x;
    float w[64];
#pragma unroll
    for (int k = 0; k < 64; ++k) w[k] = W[k * HC + t];
    for (int n = blockIdx.x; n < Nn; n += gridDim.x) {
        const float* xrow = x + (size_t)n * 64;  // uniform address
        float acc = 0.f;
#pragma unroll
        for (int k = 0; k < 64; ++k) acc += xrow[k] * w[k];
        h[(size_t)n * HC + t] = __float2half(acc);
        if (t < 8) {
            float a = 0.f;
#pragma unroll
            for (int k = 0; k < 64; ++k) a += xrow[k] * PQ[k * 8 + t];
            if (t < 4) a_src[n * 4 + t] = a;
            else a_dst[n * 4 + (t - 4)] = a;
        }
    }
}

// ---------------------------------------------------------------------------
// bucket-by-dst: edges[pos] = {src, edge_attr bits}; logits deferred to aggregate
__global__ void sortscatter_kernel(const int* __restrict__ ei,
                                   const float* __restrict__ edge_attr,
                                   const float* __restrict__ mean_acc,
                                   int* __restrict__ cursor,
                                   int2* __restrict__ edges, int Nn, int Ee) {
    int i = blockIdx.x * blockDim.x + threadIdx.x;
    int tot = Ee + Nn;
    if (i >= tot) return;
    int src, dst;
    float ea;
    if (i < Ee) {
        src = ei[i];
        dst = ei[Ee + i];
        ea = edge_attr[i];
    } else {  // self-loop, fill_value = mean(edge_attr)
        src = dst = i - Ee;
        ea = mean_acc[0] * (1.0f / (float)Ee);
    }
    int pos = atomicAdd(&cursor[dst], 1);
    edges[pos] = make_int2(src, __float_as_int(ea));
}

// ---------------------------------------------------------------------------
// one wave per dst node, SINGLE pass (softmax is shift-invariant; |logit|<~20
// so exp() cannot overflow fp32): wgt=exp(leaky(a_src[src]+a_dst[n]+ea*K));
// acc += wgt * h[src] (fp16 512B coalesced row); normalize, head-mean, bias,
// relu, residual. Edge loop unrolled x4 for memory-level parallelism.
__global__ __launch_bounds__(256) void aggregate_kernel(
    const int* __restrict__ off, const int2* __restrict__ edges,
    const float* __restrict__ a_src, const float* __restrict__ a_dst,
    const float* __restrict__ Kh, const __half* __restrict__ h,
    const float* __restrict__ bias, const float* __restrict__ x,
    float* __restrict__ out, int Nn) {
    int lane = threadIdx.x & 63;
    int n = blockIdx.x * 4 + (threadIdx.x >> 6);
    if (n >= Nn) return;
    int o0 = off[n], o1 = off[n + 1];
    int deg = o1 - o0;
    int head = lane >> 4;
    float ad = a_dst[n * 4 + head];
    float K = Kh[head];
    const uint2* h2 = (const uint2*)h;
    float4 acc = make_float4(0.f, 0.f, 0.f, 0.f);
    float swgt = 0.f;

    int i = 0;
    for (; i + 4 <= deg; i += 4) {
        int2 e0 = edges[o0 + i + 0];
        int2 e1 = edges[o0 + i + 1];
        int2 e2 = edges[o0 + i + 2];
        int2 e3 = edges[o0 + i + 3];
        uint2 hv0 = h2[(size_t)e0.x * 64 + lane];
        uint2 hv1 = h2[(size_t)e1.x * 64 + lane];
        uint2 hv2 = h2[(size_t)e2.x * 64 + lane];
        uint2 hv3 = h2[(size_t)e3.x * 64 + lane];
        float as0 = a_src[e0.x * 4 + head];
        float as1 = a_src[e1.x * 4 + head];
        float as2 = a_src[e2.x * 4 + head];
        float as3 = a_src[e3.x * 4 + head];
        float l0 = as0 + ad + __int_as_float(e0.y) * K;
        float l1 = as1 + ad + __int_as_float(e1.y) * K;
        float l2 = as2 + ad + __int_as_float(e2.y) * K;
        float l3 = as3 + ad + __int_as_float(e3.y) * K;
        l0 = l0 > 0.f ? l0 : NEG * l0;
        l1 = l1 > 0.f ? l1 : NEG * l1;
        l2 = l2 > 0.f ? l2 : NEG * l2;
        l3 = l3 > 0.f ? l3 : NEG * l3;
        float w0 = __expf(l0), w1 = __expf(l1), w2 = __expf(l2), w3 = __expf(l3);
        swgt += (w0 + w1) + (w2 + w3);
        float2 f;
        f = __half22float2(*reinterpret_cast<const __half2*>(&hv0.x));
        acc.x += w0 * f.x; acc.y += w0 * f.y;
        f = __half22float2(*reinterpret_cast<const __half2*>(&hv0.y));
        acc.z += w0 * f.x; acc.w += w0 * f.y;
        f = __half22float2(*reinterpret_cast<const __half2*>(&hv1.x));
        acc.x += w1 * f.x; acc.y += w1 * f.y;
        f = __half22float2(*reinterpret_cast<const __half2*>(&hv1.y));
        acc.z += w1 * f.x; acc.w += w1 * f.y;
        f = __half22float2(*reinterpret_cast<const __half2*>(&hv2.x));
        acc.x += w2 * f.x; acc.y += w2 * f.y;
        f = __half22float2(*reinterpret_cast<const __half2*>(&hv2.y));
        acc.z += w2 * f.x; acc.w += w2 * f.y;
        f = __half22float2(*reinterpret_cast<const __half2*>(&hv3.x));
        acc.x += w3 * f.x; acc.y += w3 * f.y;
        f = __half22float2(*reinterpret_cast<const __half2*>(&hv3.y));
        acc.z += w3 * f.x; acc.w += w3 * f.y;
    }
    for (; i < deg; ++i) {
        int2 e = edges[o0 + i];
        uint2 hv = h2[(size_t)e.x * 64 + lane];
        float as = a_src[e.x * 4 + head];
        float l = as + ad + __int_as_float(e.y) * K;
        l = l > 0.f ? l : NEG * l;
        float wg = __expf(l);
        swgt += wg;
        float2 f;
        f = __half22float2(*reinterpret_cast<const __half2*>(&hv.x));
        acc.x += wg * f.x; acc.y += wg * f.y;
        f = __half22float2(*reinterpret_cast<const __half2*>(&hv.y));
        acc.z += wg * f.x; acc.w += wg * f.y;
    }

    float inv = 1.f / (swgt + 1e-16f);
    acc.x *= inv; acc.y *= inv; acc.z *= inv; acc.w *= inv;

    // head-mean: sum lanes {l, l^16, l^32, l^48} (same channels, different heads)
    acc.x += __shfl_xor(acc.x, 16);
    acc.y += __shfl_xor(acc.y, 16);
    acc.z += __shfl_xor(acc.z, 16);
    acc.w += __shfl_xor(acc.w, 16);
    acc.x += __shfl_xor(acc.x, 32);
    acc.y += __shfl_xor(acc.y, 32);
    acc.z += __shfl_xor(acc.z, 32);
    acc.w += __shfl_xor(acc.w, 32);
    if (lane < 16) {
        float4 b = ((const float4*)bias)[lane];
        float4 xv = ((const float4*)x)[(size_t)n * 16 + lane];
        float4 o;
        o.x = fmaxf(acc.x * 0.25f + b.x, 0.f) + xv.x;
        o.y = fmaxf(acc.y * 0.25f + b.y, 0.f) + xv.y;
        o.z = fmaxf(acc.z * 0.25f + b.z, 0.f) + xv.z;
        o.w = fmaxf(acc.w * 0.25f + b.w, 0.f) + xv.w;
        ((float4*)out)[(size_t)n * 16 + lane] = o;
    }
}

// ---------------------------------------------------------------------------
extern "C" void kernel_launch(void* const* d_in, const int* in_sizes, int n_in,
                              void* d_out, int out_size, void* d_ws, size_t ws_size,
                              hipStream_t stream) {
    const float* x = (const float*)d_in[0];
    const int* ei = (const int*)d_in[1];
    const float* edge_attr = (const float*)d_in[2];
    const float* W = (const float*)d_in[3];
    const float* att_src = (const float*)d_in[4];
    const float* att_dst = (const float*)d_in[5];
    const float* lin_edge_w = (const float*)d_in[6];
    const float* att_edge = (const float*)d_in[7];
    const float* bias = (const float*)d_in[8];
    float* out = (float*)d_out;
    int Nn = in_sizes[0] / 64;
    int Ee = in_sizes[1] / 2;
    int tot = Ee + Nn;
    int numBlocks = (Nn + 255) / 256;  // 196 for N=50000; scan2 handles <=256

    char* p = (char*)d_ws;
    size_t o = 0;
    auto alloc = [&](size_t bytes) -> char* {
        char* r = p + o;
        o += (bytes + 255) & ~(size_t)255;
        return r;
    };
    float* mean_acc = (float*)alloc(256);               // zeroed below
    int* counts = (int*)alloc((size_t)Nn * 4);          // zeroed below
    size_t zero_bytes = o;
    float* Kh = (float*)alloc(256);                     // [H]
    float* PQ = (float*)alloc(512 * 4);                 // [64][8] projection
    int* blockSums = (int*)alloc((size_t)numBlocks * 4);
    int* blockOff = (int*)alloc((size_t)numBlocks * 4);
    int* off = (int*)alloc((size_t)(Nn + 1) * 4);       // [N+1] CSR offsets
    int* cursor = (int*)alloc((size_t)Nn * 4);          // [N] bucket cursors
    int2* edges = (int2*)alloc((size_t)tot * 8);        // [tot] {src, ea} by dst
    __half* h = (__half*)alloc((size_t)Nn * HC * 2);    // [N,H,C] fp16
    float* a_src = (float*)alloc((size_t)Nn * H * 4);
    float* a_dst = (float*)alloc((size_t)Nn * H * 4);
    (void)ws_size;

    hipMemsetAsync(d_ws, 0, zero_bytes, stream);
    init_kernel<<<512, 256, 0, stream>>>(ei, edge_attr, lin_edge_w, att_edge, W,
                                         att_src, att_dst, counts, mean_acc, Kh, PQ, Ee);
    gemm_kernel<<<2048, 256, 0, stream>>>(x, W, PQ, h, a_src, a_dst, Nn);
    scan1_kernel<<<numBlocks, 256, 0, stream>>>(counts, blockSums, Nn);
    scan2_kernel<<<1, 256, 0, stream>>>(blockSums, blockOff, off, numBlocks, Nn);
    scan3_kernel<<<numBlocks, 256, 0, stream>>>(counts, blockOff, off, cursor, Nn);
    sortscatter_kernel<<<(tot + 255) / 256, 256, 0, stream>>>(
        ei, edge_attr, mean_acc, cursor, edges, Nn, Ee);
    aggregate_kernel<<<(Nn + 3) / 4, 256, 0, stream>>>(off, edges, a_src, a_dst,
                                                       Kh, h, bias, x, out, Nn);
}

// Round 5
// 285.465 us; speedup vs baseline: 1.2933x; 1.2933x over previous
//
#include <hip/hip_runtime.h>
#include <hip/hip_fp16.h>
#include <math.h>

#define H 4
#define C 64
#define HC 256
#define NEG 0.2f

// ---------------------------------------------------------------------------
// init: dst histogram (counts pre-zeroed; self-loop +1 folded into scan),
// partial sum of edge_attr, Kh[h]=dot(lin_edge_w[h],att_edge[h]),
// PQT[o][k] = sum_c W[k][(o&3)*64+c] * att_{src|dst}[(o&3)][c]  (o<4: src)
__global__ void init_kernel(const int* __restrict__ ei,
                            const float* __restrict__ edge_attr,
                            const float* __restrict__ lin_edge_w,
                            const float* __restrict__ att_edge,
                            const float* __restrict__ W,
                            const float* __restrict__ att_src,
                            const float* __restrict__ att_dst,
                            int* __restrict__ counts, float* __restrict__ mean_acc,
                            float* __restrict__ Kh, float* __restrict__ PQT, int Ee) {
    int gid = blockIdx.x * blockDim.x + threadIdx.x;
    int stride = gridDim.x * blockDim.x;
    float s = 0.f;
    for (int i = gid; i < Ee; i += stride) {
        s += edge_attr[i];
        atomicAdd(&counts[ei[Ee + i]], 1);
    }
    __shared__ float red[256];
    red[threadIdx.x] = s;
    __syncthreads();
    for (int off = 128; off; off >>= 1) {
        if (threadIdx.x < off) red[threadIdx.x] += red[threadIdx.x + off];
        __syncthreads();
    }
    if (threadIdx.x == 0) atomicAdd(mean_acc, red[0]);
    if (gid < H) {
        float k = 0.f;
        for (int c = 0; c < C; ++c) k += lin_edge_w[gid * C + c] * att_edge[gid * C + c];
        Kh[gid] = k;
    }
    if (gid < 512) {
        int o = gid >> 6, k = gid & 63;
        const float* att = (o < 4) ? att_src + o * C : att_dst + (o - 4) * C;
        const float* wr = W + k * HC + (o & 3) * C;
        float a = 0.f;
        for (int c = 0; c < C; ++c) a += wr[c] * att[c];
        PQT[gid] = a;  // o-major: PQT[o*64+k]
    }
}

// ---------------------------------------------------------------------------
// hierarchical scan of (counts[i] + 1) over Nn elements, 256/block
__global__ __launch_bounds__(256) void scan1_kernel(const int* __restrict__ counts,
                                                    int* __restrict__ blockSums, int Nn) {
    int idx = blockIdx.x * 256 + threadIdx.x;
    int v = (idx < Nn) ? counts[idx] + 1 : 0;
#pragma unroll
    for (int off = 32; off; off >>= 1) v += __shfl_down(v, off);
    __shared__ int ws[4];
    if ((threadIdx.x & 63) == 0) ws[threadIdx.x >> 6] = v;
    __syncthreads();
    if (threadIdx.x == 0) blockSums[blockIdx.x] = ws[0] + ws[1] + ws[2] + ws[3];
}

__global__ __launch_bounds__(256) void scan2_kernel(int* __restrict__ blockSums,
                                                    int* __restrict__ blockOff,
                                                    int* __restrict__ off,
                                                    int numBlocks, int Nn) {
    __shared__ int buf[2][256];
    int t = threadIdx.x;
    int v = (t < numBlocks) ? blockSums[t] : 0;
    buf[0][t] = v;
    __syncthreads();
    int pp = 0;
#pragma unroll
    for (int d = 1; d < 256; d <<= 1) {
        int nv = buf[pp][t];
        if (t >= d) nv += buf[pp][t - d];
        buf[pp ^ 1][t] = nv;
        pp ^= 1;
        __syncthreads();
    }
    int incl = buf[pp][t];
    if (t < numBlocks) blockOff[t] = incl - v;
    if (t == 255) off[Nn] = incl;  // grand total
}

__global__ __launch_bounds__(256) void scan3_kernel(const int* __restrict__ counts,
                                                    const int* __restrict__ blockOff,
                                                    int* __restrict__ off,
                                                    int* __restrict__ cursor, int Nn) {
    __shared__ int buf[2][256];
    int t = threadIdx.x;
    int idx = blockIdx.x * 256 + t;
    int v = (idx < Nn) ? counts[idx] + 1 : 0;
    buf[0][t] = v;
    __syncthreads();
    int pp = 0;
#pragma unroll
    for (int d = 1; d < 256; d <<= 1) {
        int nv = buf[pp][t];
        if (t >= d) nv += buf[pp][t - d];
        buf[pp ^ 1][t] = nv;
        pp ^= 1;
        __syncthreads();
    }
    if (idx < Nn) {
        int excl = blockOff[blockIdx.x] + buf[pp][t] - v;
        off[idx] = excl;
        cursor[idx] = excl;
    }
}

// ---------------------------------------------------------------------------
// h = x @ W (fp16 out). 4 nodes per barrier pair: wave 0 stages 1KB (4 rows)
// as float4; every thread does 4x(16 ds_read_b128 broadcast + 64 FMA) against
// its register-resident W column. Threads 0..31 also project the staged rows
// through PQT -> a_src/a_dst (no shuffles, no scalar loads).
__global__ __launch_bounds__(256) void gemm_kernel(
    const float* __restrict__ x, const float* __restrict__ W,
    const float* __restrict__ PQT, __half* __restrict__ h,
    float* __restrict__ a_src, float* __restrict__ a_dst, int Nn) {
    int t = threadIdx.x;
    float w[64];
#pragma unroll
    for (int k = 0; k < 64; ++k) w[k] = W[k * HC + t];
    __shared__ float xs[256];
    int nGroups = (Nn + 3) >> 2;
    for (int g = blockIdx.x; g < nGroups; g += gridDim.x) {
        __syncthreads();
        if (t < 64) {
            size_t base = (size_t)g * 256 + t * 4;
            if (base < (size_t)Nn * 64)
                ((float4*)xs)[t] = *(const float4*)(x + base);
        }
        __syncthreads();
        int nd_max = min(4, Nn - g * 4);
#pragma unroll
        for (int nd = 0; nd < 4; ++nd) {
            if (nd >= nd_max) break;
            float a = 0.f;
#pragma unroll
            for (int k = 0; k < 64; k += 4) {
                float4 xv = *(const float4*)&xs[nd * 64 + k];
                a += xv.x * w[k] + xv.y * w[k + 1] + xv.z * w[k + 2] + xv.w * w[k + 3];
            }
            h[((size_t)g * 4 + nd) * HC + t] = __float2half(a);
        }
        if (t < 32) {
            int nd = t >> 3, o = t & 7;
            if (nd < nd_max) {
                int node = g * 4 + nd;
                float a = 0.f;
#pragma unroll
                for (int k = 0; k < 64; k += 4) {
                    float4 xv = *(const float4*)&xs[nd * 64 + k];
                    float4 pq = *(const float4*)&PQT[o * 64 + k];
                    a += xv.x * pq.x + xv.y * pq.y + xv.z * pq.z + xv.w * pq.w;
                }
                if (o < 4) a_src[node * 4 + o] = a;
                else a_dst[node * 4 + (o - 4)] = a;
            }
        }
    }
}

// ---------------------------------------------------------------------------
// bucket-by-dst: edges[pos] = {src, edge_attr bits}; logits deferred to aggregate
__global__ void sortscatter_kernel(const int* __restrict__ ei,
                                   const float* __restrict__ edge_attr,
                                   const float* __restrict__ mean_acc,
                                   int* __restrict__ cursor,
                                   int2* __restrict__ edges, int Nn, int Ee) {
    int i = blockIdx.x * blockDim.x + threadIdx.x;
    int tot = Ee + Nn;
    if (i >= tot) return;
    int src, dst;
    float ea;
    if (i < Ee) {
        src = ei[i];
        dst = ei[Ee + i];
        ea = edge_attr[i];
    } else {  // self-loop, fill_value = mean(edge_attr)
        src = dst = i - Ee;
        ea = mean_acc[0] * (1.0f / (float)Ee);
    }
    int pos = atomicAdd(&cursor[dst], 1);
    edges[pos] = make_int2(src, __float_as_int(ea));
}

// ---------------------------------------------------------------------------
// one wave per dst node, single pass (softmax shift-invariance; |logit| << 88
// so fp32 exp cannot overflow): wgt=exp(leaky(a_src[src]+a_dst[n]+ea*K));
// acc += wgt * h[src] (fp16 512B coalesced row, v_fma_mix-friendly form);
// normalize, head-mean, bias, relu, residual. Edge loop unrolled x4 for MLP.
__global__ __launch_bounds__(256) void aggregate_kernel(
    const int* __restrict__ off, const int2* __restrict__ edges,
    const float* __restrict__ a_src, const float* __restrict__ a_dst,
    const float* __restrict__ Kh, const __half* __restrict__ h,
    const float* __restrict__ bias, const float* __restrict__ x,
    float* __restrict__ out, int Nn) {
    int lane = threadIdx.x & 63;
    int n = blockIdx.x * 4 + (threadIdx.x >> 6);
    if (n >= Nn) return;
    int o0 = off[n], o1 = off[n + 1];
    int deg = o1 - o0;
    int head = lane >> 4;
    float ad = a_dst[n * 4 + head];
    float K = Kh[head];
    const __half2* h2 = (const __half2*)h;  // h row = 128 half2; lane reads 2
    float4 acc = make_float4(0.f, 0.f, 0.f, 0.f);
    float swgt = 0.f;

    int i = 0;
    for (; i + 4 <= deg; i += 4) {
        int2 e0 = edges[o0 + i + 0];
        int2 e1 = edges[o0 + i + 1];
        int2 e2 = edges[o0 + i + 2];
        int2 e3 = edges[o0 + i + 3];
        __half2 p0a = h2[(size_t)e0.x * 128 + lane * 2];
        __half2 p0b = h2[(size_t)e0.x * 128 + lane * 2 + 1];
        __half2 p1a = h2[(size_t)e1.x * 128 + lane * 2];
        __half2 p1b = h2[(size_t)e1.x * 128 + lane * 2 + 1];
        __half2 p2a = h2[(size_t)e2.x * 128 + lane * 2];
        __half2 p2b = h2[(size_t)e2.x * 128 + lane * 2 + 1];
        __half2 p3a = h2[(size_t)e3.x * 128 + lane * 2];
        __half2 p3b = h2[(size_t)e3.x * 128 + lane * 2 + 1];
        float as0 = a_src[e0.x * 4 + head];
        float as1 = a_src[e1.x * 4 + head];
        float as2 = a_src[e2.x * 4 + head];
        float as3 = a_src[e3.x * 4 + head];
        float l0 = as0 + ad + __int_as_float(e0.y) * K;
        float l1 = as1 + ad + __int_as_float(e1.y) * K;
        float l2 = as2 + ad + __int_as_float(e2.y) * K;
        float l3 = as3 + ad + __int_as_float(e3.y) * K;
        l0 = l0 > 0.f ? l0 : NEG * l0;
        l1 = l1 > 0.f ? l1 : NEG * l1;
        l2 = l2 > 0.f ? l2 : NEG * l2;
        l3 = l3 > 0.f ? l3 : NEG * l3;
        float w0 = __expf(l0), w1 = __expf(l1), w2 = __expf(l2), w3 = __expf(l3);
        swgt += (w0 + w1) + (w2 + w3);
        acc.x += w0 * __half2float(__low2half(p0a));
        acc.y += w0 * __half2float(__high2half(p0a));
        acc.z += w0 * __half2float(__low2half(p0b));
        acc.w += w0 * __half2float(__high2half(p0b));
        acc.x += w1 * __half2float(__low2half(p1a));
        acc.y += w1 * __half2float(__high2half(p1a));
        acc.z += w1 * __half2float(__low2half(p1b));
        acc.w += w1 * __half2float(__high2half(p1b));
        acc.x += w2 * __half2float(__low2half(p2a));
        acc.y += w2 * __half2float(__high2half(p2a));
        acc.z += w2 * __half2float(__low2half(p2b));
        acc.w += w2 * __half2float(__high2half(p2b));
        acc.x += w3 * __half2float(__low2half(p3a));
        acc.y += w3 * __half2float(__high2half(p3a));
        acc.z += w3 * __half2float(__low2half(p3b));
        acc.w += w3 * __half2float(__high2half(p3b));
    }
    for (; i < deg; ++i) {
        int2 e = edges[o0 + i];
        __half2 pa = h2[(size_t)e.x * 128 + lane * 2];
        __half2 pb = h2[(size_t)e.x * 128 + lane * 2 + 1];
        float as = a_src[e.x * 4 + head];
        float l = as + ad + __int_as_float(e.y) * K;
        l = l > 0.f ? l : NEG * l;
        float wg = __expf(l);
        swgt += wg;
        acc.x += wg * __half2float(__low2half(pa));
        acc.y += wg * __half2float(__high2half(pa));
        acc.z += wg * __half2float(__low2half(pb));
        acc.w += wg * __half2float(__high2half(pb));
    }

    float inv = 1.f / (swgt + 1e-16f);
    acc.x *= inv; acc.y *= inv; acc.z *= inv; acc.w *= inv;

    // head-mean: sum lanes {l, l^16, l^32, l^48} (same channels, different heads)
    acc.x += __shfl_xor(acc.x, 16);
    acc.y += __shfl_xor(acc.y, 16);
    acc.z += __shfl_xor(acc.z, 16);
    acc.w += __shfl_xor(acc.w, 16);
    acc.x += __shfl_xor(acc.x, 32);
    acc.y += __shfl_xor(acc.y, 32);
    acc.z += __shfl_xor(acc.z, 32);
    acc.w += __shfl_xor(acc.w, 32);
    if (lane < 16) {
        float4 b = ((const float4*)bias)[lane];
        float4 xv = ((const float4*)x)[(size_t)n * 16 + lane];
        float4 o;
        o.x = fmaxf(acc.x * 0.25f + b.x, 0.f) + xv.x;
        o.y = fmaxf(acc.y * 0.25f + b.y, 0.f) + xv.y;
        o.z = fmaxf(acc.z * 0.25f + b.z, 0.f) + xv.z;
        o.w = fmaxf(acc.w * 0.25f + b.w, 0.f) + xv.w;
        ((float4*)out)[(size_t)n * 16 + lane] = o;
    }
}

// ---------------------------------------------------------------------------
extern "C" void kernel_launch(void* const* d_in, const int* in_sizes, int n_in,
                              void* d_out, int out_size, void* d_ws, size_t ws_size,
                              hipStream_t stream) {
    const float* x = (const float*)d_in[0];
    const int* ei = (const int*)d_in[1];
    const float* edge_attr = (const float*)d_in[2];
    const float* W = (const float*)d_in[3];
    const float* att_src = (const float*)d_in[4];
    const float* att_dst = (const float*)d_in[5];
    const float* lin_edge_w = (const float*)d_in[6];
    const float* att_edge = (const float*)d_in[7];
    const float* bias = (const float*)d_in[8];
    float* out = (float*)d_out;
    int Nn = in_sizes[0] / 64;
    int Ee = in_sizes[1] / 2;
    int tot = Ee + Nn;
    int numBlocks = (Nn + 255) / 256;  // 196 for N=50000; scan2 handles <=256

    char* p = (char*)d_ws;
    size_t o = 0;
    auto alloc = [&](size_t bytes) -> char* {
        char* r = p + o;
        o += (bytes + 255) & ~(size_t)255;
        return r;
    };
    float* mean_acc = (float*)alloc(256);               // zeroed below
    int* counts = (int*)alloc((size_t)Nn * 4);          // zeroed below
    size_t zero_bytes = o;
    float* Kh = (float*)alloc(256);                     // [H]
    float* PQT = (float*)alloc(512 * 4);                // [8][64] projection
    int* blockSums = (int*)alloc((size_t)numBlocks * 4);
    int* blockOff = (int*)alloc((size_t)numBlocks * 4);
    int* off = (int*)alloc((size_t)(Nn + 1) * 4);       // [N+1] CSR offsets
    int* cursor = (int*)alloc((size_t)Nn * 4);          // [N] bucket cursors
    int2* edges = (int2*)alloc((size_t)tot * 8);        // [tot] {src, ea} by dst
    __half* h = (__half*)alloc((size_t)Nn * HC * 2);    // [N,H,C] fp16
    float* a_src = (float*)alloc((size_t)Nn * H * 4);
    float* a_dst = (float*)alloc((size_t)Nn * H * 4);
    (void)ws_size;

    hipMemsetAsync(d_ws, 0, zero_bytes, stream);
    init_kernel<<<512, 256, 0, stream>>>(ei, edge_attr, lin_edge_w, att_edge, W,
                                         att_src, att_dst, counts, mean_acc, Kh, PQT, Ee);
    gemm_kernel<<<2048, 256, 0, stream>>>(x, W, PQT, h, a_src, a_dst, Nn);
    scan1_kernel<<<numBlocks, 256, 0, stream>>>(counts, blockSums, Nn);
    scan2_kernel<<<1, 256, 0, stream>>>(blockSums, blockOff, off, numBlocks, Nn);
    scan3_kernel<<<numBlocks, 256, 0, stream>>>(counts, blockOff, off, cursor, Nn);
    sortscatter_kernel<<<(tot + 255) / 256, 256, 0, stream>>>(
        ei, edge_attr, mean_acc, cursor, edges, Nn, Ee);
    aggregate_kernel<<<(Nn + 3) / 4, 256, 0, stream>>>(off, edges, a_src, a_dst,
                                                       Kh, h, bias, x, out, Nn);
}